// Round 11
// baseline (460.650 us; speedup 1.0000x reference)
//
#include <hip/hip_runtime.h>

#define SLOPE 0.2f
#define BN_EPS 1e-5f

#define CSR_TILE 4096       // edges per tile (phase A/C)
#define NBUCK_SH 9          // bucket = dst >> 9  (512 nodes per bucket)

typedef __attribute__((ext_vector_type(8))) short bf16x8;
typedef __attribute__((ext_vector_type(4))) float f32x4;

__device__ __forceinline__ float wave_sum(float v){
  #pragma unroll
  for(int o=32;o;o>>=1) v += __shfl_xor(v,o);
  return v;
}
__device__ __forceinline__ float wave_max(float v){
  #pragma unroll
  for(int o=32;o;o>>=1) v = fmaxf(v,__shfl_xor(v,o));
  return v;
}
__device__ __forceinline__ unsigned pack_bf16(float a, float b){
  unsigned ua=__float_as_uint(a), ub=__float_as_uint(b);
  ua += 0x7fffu + ((ua>>16)&1u);
  ub += 0x7fffu + ((ub>>16)&1u);
  return (ua>>16) | (ub & 0xffff0000u);
}
__device__ __forceinline__ float bf_lo(unsigned u){ return __uint_as_float(u<<16); }
__device__ __forceinline__ float bf_hi(unsigned u){ return __uint_as_float(u & 0xffff0000u); }

// ---------------- both weight transposes in one launch
__global__ __launch_bounds__(256) void wtrans2(const float* __restrict__ W0,
    const float* __restrict__ W1, unsigned* __restrict__ Wt0, unsigned* __restrict__ Wt1){
  int idx = blockIdx.x*256 + threadIdx.x;
  if(blockIdx.x < 64){
    int c = idx >> 7, kp = idx & 127;          // W0: K=256 -> 128 kpairs
    Wt0[(size_t)c*128 + kp] = pack_bf16(W0[(size_t)(2*kp)*128 + c], W0[(size_t)(2*kp+1)*128 + c]);
  } else {
    int i2 = idx - 64*256;
    int c = i2 >> 6, kp = i2 & 63;             // W1: K=128 -> 64 kpairs
    Wt1[(size_t)c*64 + kp] = pack_bf16(W1[(size_t)(2*kp)*128 + c], W1[(size_t)(2*kp+1)*128 + c]);
  }
}

// ---------------- MFMA GEMM: A[n,K] @ W[K,128] -> bf16-packed out[n][64 uints]
// 128x128 tile, 4 waves (64x64 quadrant each, 4x4 frags), register prefetch
// across K-tiles, LDS-staged coalesced epilogue (C + fused el/er).
template<int AF32>
__global__ __launch_bounds__(256) void gemm_mfma(const void* __restrict__ Aptr,
    const unsigned* __restrict__ Wt, unsigned* __restrict__ outb,
    const float* __restrict__ al, const float* __restrict__ ar,
    float* __restrict__ el, float* __restrict__ er, int n, int K){
  __shared__ unsigned lds[2*128*36];   // 36864 B: sA | sB, reused by epilogue
  int t = threadIdx.x;
  int w = t >> 6, l = t & 63;
  int wr = (w >> 1) * 64, wc = (w & 1) * 64;   // wave quadrant
  int row0 = blockIdx.x * 128;
  int K2 = K >> 1;
  int ktiles = K >> 6;                 // K-tile = 64 elems = 32 kpairs

  // staging: A = 1024 uint4 (4/thread), B = 1024 uint4 (4/thread)
  int srow[4], sslot[4];
  #pragma unroll
  for(int i=0;i<4;i++){ int u4 = t + i*256; srow[i] = u4>>3; sslot[i] = u4&7; }

  uint4 pa[4][2];   // f32 path uses both halves; bf16 path uses [i][0]
  uint4 pb[4];

  auto load_tile = [&](int kt){
    if(AF32){
      const float* A = (const float*)Aptr;
      #pragma unroll
      for(int i=0;i<4;i++){
        int gr = row0 + srow[i];
        pa[i][0] = make_uint4(0,0,0,0);
        pa[i][1] = make_uint4(0,0,0,0);
        if(gr < n){
          const unsigned* ap = (const unsigned*)(A + (size_t)gr*K + kt*64 + sslot[i]*8);
          pa[i][0] = *(const uint4*)ap;
          pa[i][1] = *(const uint4*)(ap+4);
        }
      }
    } else {
      const unsigned* A = (const unsigned*)Aptr;
      #pragma unroll
      for(int i=0;i<4;i++){
        int gr = row0 + srow[i];
        pa[i][0] = make_uint4(0,0,0,0);
        if(gr < n) pa[i][0] = *(const uint4*)(A + (size_t)gr*K2 + kt*32 + sslot[i]*4);
      }
    }
    #pragma unroll
    for(int i=0;i<4;i++)
      pb[i] = *(const uint4*)(Wt + (size_t)srow[i]*K2 + kt*32 + sslot[i]*4);
  };

  auto store_tile = [&](){
    if(AF32){
      #pragma unroll
      for(int i=0;i<4;i++){
        uint4 v;
        v.x = pack_bf16(__uint_as_float(pa[i][0].x), __uint_as_float(pa[i][0].y));
        v.y = pack_bf16(__uint_as_float(pa[i][0].z), __uint_as_float(pa[i][0].w));
        v.z = pack_bf16(__uint_as_float(pa[i][1].x), __uint_as_float(pa[i][1].y));
        v.w = pack_bf16(__uint_as_float(pa[i][1].z), __uint_as_float(pa[i][1].w));
        *(uint4*)&lds[srow[i]*36 + sslot[i]*4] = v;
      }
    } else {
      #pragma unroll
      for(int i=0;i<4;i++)
        *(uint4*)&lds[srow[i]*36 + sslot[i]*4] = pa[i][0];
    }
    #pragma unroll
    for(int i=0;i<4;i++)
      *(uint4*)&lds[128*36 + srow[i]*36 + sslot[i]*4] = pb[i];
  };

  f32x4 zero4 = {0.f,0.f,0.f,0.f};
  f32x4 acc[4][4];
  #pragma unroll
  for(int i=0;i<4;i++)
    #pragma unroll
    for(int j=0;j<4;j++) acc[i][j] = zero4;

  int rl = l & 15;
  load_tile(0);
  for(int kt = 0; kt < ktiles; ++kt){
    store_tile();
    __syncthreads();
    if(kt+1 < ktiles) load_tile(kt+1);   // in flight during MFMA below
    #pragma unroll
    for(int ks=0; ks<2; ++ks){
      int koff = ks*16 + (l>>4)*4;
      bf16x8 a[4], b[4];
      #pragma unroll
      for(int f=0; f<4; f++){
        a[f] = *(const bf16x8*)&lds[(wr + f*16 + rl)*36 + koff];
        b[f] = *(const bf16x8*)&lds[128*36 + (wc + f*16 + rl)*36 + koff];
      }
      #pragma unroll
      for(int i=0;i<4;i++)
        #pragma unroll
        for(int j=0;j<4;j++)
          acc[i][j] = __builtin_amdgcn_mfma_f32_16x16x32_bf16(a[i], b[j], acc[i][j], 0, 0, 0);
    }
    __syncthreads();
  }

  // ---- epilogue: stage C + el/er in LDS, then full-line coalesced writes ----
  // sC: 128 rows x 68-uint stride = 34816 B; el/er: 2 x 1024 B after it.
  float* sel = (float*)&lds[8704];     // byte 34816
  float* ser = sel + 256;

  // el/er: wave covers head h = wc>>6 for rows wr..wr+63; 16-lane-group reduce
  {
    int h = wc >> 6;
    float alv[4], arv[4];
    #pragma unroll
    for(int j=0;j<4;j++){
      int c = wc + j*16 + (l&15);
      alv[j] = al[c]; arv[j] = ar[c];
    }
    #pragma unroll
    for(int i=0;i<4;i++){
      #pragma unroll
      for(int g=0;g<4;g++){
        float pe = acc[i][0][g]*alv[0] + acc[i][1][g]*alv[1]
                 + acc[i][2][g]*alv[2] + acc[i][3][g]*alv[3];
        float qe = acc[i][0][g]*arv[0] + acc[i][1][g]*arv[1]
                 + acc[i][2][g]*arv[2] + acc[i][3][g]*arv[3];
        #pragma unroll
        for(int o=8;o;o>>=1){ pe += __shfl_xor(pe,o); qe += __shfl_xor(qe,o); }
        if((l & 15) == 0){
          int r = wr + i*16 + (l>>4)*4 + g;
          sel[r*2+h] = pe;
          ser[r*2+h] = qe;
        }
      }
    }
  }
  // pack C col-pairs via shfl, stage into sC (overwrites K-staging area)
  #pragma unroll
  for(int i=0;i<4;i++){
    #pragma unroll
    for(int j=0;j<4;j++){
      #pragma unroll
      for(int g=0;g<4;g++){
        float v  = acc[i][j][g];
        float vp = __shfl_xor(v, 1);
        if(!(l & 1)){
          int r = wr + i*16 + (l>>4)*4 + g;
          lds[r*68 + wc/2 + j*8 + ((l&15)>>1)] = pack_bf16(v, vp);
        }
      }
    }
  }
  __syncthreads();
  // linear coalesced writes: C (uint4 x8/thread), el/er (float2/row)
  #pragma unroll
  for(int it=0; it<8; ++it){
    int idx = t + it*256;
    int r = idx >> 4;
    int q = (idx & 15) * 4;
    int gr = row0 + r;
    if(gr < n) *(uint4*)&outb[(size_t)gr*64 + q] = *(const uint4*)&lds[r*68 + q];
  }
  if(t < 128){
    int gr = row0 + t;
    if(gr < n) *(float2*)&el[(size_t)gr*2] = *(const float2*)&sel[t*2];
  } else {
    int r = t - 128;
    int gr = row0 + r;
    if(gr < n) *(float2*)&er[(size_t)gr*2] = *(const float2*)&ser[r*2];
  }
}

// ================= CSR build: two-level counting sort =================
__global__ __launch_bounds__(256) void csrA(const int* __restrict__ dst,
    int* __restrict__ thist, int E, int nbuck, int ntiles){
  __shared__ int h[512];
  int t = threadIdx.x;
  if(t < nbuck) h[t] = 0;
  __syncthreads();
  int base = blockIdx.x * CSR_TILE;
  for(int k = 0; k < CSR_TILE/256; ++k){
    int e = base + k*256 + t;
    if(e < E) atomicAdd(&h[dst[e] >> NBUCK_SH], 1);
  }
  __syncthreads();
  if(t < nbuck) thist[blockIdx.x*nbuck + t] = h[t];
}

__global__ __launch_bounds__(512) void csrB1(const int* __restrict__ thist,
    int* __restrict__ off, int* __restrict__ btotal, int nbuck, int ntiles){
  __shared__ int ls[512];
  int t = threadIdx.x;
  int b = blockIdx.x;
  int v = (t < ntiles) ? thist[(size_t)t*nbuck + b] : 0;
  ls[t] = v; __syncthreads();
  for(int o=1;o<512;o<<=1){
    int x = (t>=o) ? ls[t-o] : 0;
    __syncthreads();
    ls[t] += x;
    __syncthreads();
  }
  if(t < ntiles) off[(size_t)b*ntiles + t] = ls[t] - v;
  if(t == 511) btotal[b] = ls[511];
}

__global__ __launch_bounds__(256) void csrB2(const int* __restrict__ btotal,
    int* __restrict__ bbase, int nbuck, int E){
  __shared__ int ls[256];
  int t = threadIdx.x;
  int v = (t < nbuck) ? btotal[t] : 0;
  ls[t] = v; __syncthreads();
  for(int o=1;o<256;o<<=1){
    int x = (t>=o) ? ls[t-o] : 0;
    __syncthreads();
    ls[t] += x;
    __syncthreads();
  }
  if(t < nbuck) bbase[t] = ls[t] - v;
  if(t == 0) bbase[nbuck] = E;
}

__global__ __launch_bounds__(256) void csrC(const int* __restrict__ src,
    const int* __restrict__ dst, const int* __restrict__ off,
    const int* __restrict__ bbase, unsigned* __restrict__ tmp,
    int E, int nbuck, int ntiles){
  __shared__ int basel[512];
  __shared__ int cnt[512];
  int t = threadIdx.x;
  int tile = blockIdx.x;
  if(t < nbuck){
    basel[t] = bbase[t] + off[(size_t)t*ntiles + tile];
    cnt[t] = 0;
  }
  __syncthreads();
  int base = tile * CSR_TILE;
  for(int k = 0; k < CSR_TILE/256; ++k){
    int e = base + k*256 + t;
    if(e < E){
      int d = dst[e];
      int s = src[e];
      int b = d >> NBUCK_SH;
      int r = atomicAdd(&cnt[b], 1);
      tmp[basel[b] + r] = (unsigned)s | ((unsigned)(d & ((1<<NBUCK_SH)-1)) << 17);
    }
  }
}

__global__ __launch_bounds__(512) void csrD(const unsigned* __restrict__ tmp,
    const int* __restrict__ bbase, int* __restrict__ rowptr,
    int* __restrict__ esrc, int N, int E, int nbuck){
  __shared__ int hist[512];
  __shared__ int ls[512];
  int t = threadIdx.x;
  int b = blockIdx.x;
  int base = bbase[b];
  int cnt  = bbase[b+1] - base;
  int n0   = b << NBUCK_SH;
  int nn   = min(512, N - n0);
  hist[t] = 0;
  __syncthreads();
  for(int i = t; i < cnt; i += 512)
    atomicAdd(&hist[tmp[base+i] >> 17], 1);
  __syncthreads();
  int v = hist[t];
  ls[t] = v; __syncthreads();
  for(int o=1;o<512;o<<=1){
    int x = (t>=o) ? ls[t-o] : 0;
    __syncthreads();
    ls[t] += x;
    __syncthreads();
  }
  int rp = ls[t] - v;
  if(t < nn) rowptr[n0 + t] = base + rp;
  if(b == nbuck-1 && t == 0) rowptr[N] = E;
  __syncthreads();
  hist[t] = rp;
  __syncthreads();
  for(int i = t; i < cnt; i += 512){
    unsigned v2 = tmp[base+i];
    int dl = v2 >> 17;
    int s  = v2 & 0x1FFFF;
    int r  = atomicAdd(&hist[dl], 1);
    esrc[base + r] = s;
  }
}

// ---- 8-deep gather/accumulate over one ≤64-edge chunk; zero-weight lanes pad the tail
__device__ __forceinline__ void agg_chunk(const unsigned* __restrict__ featb,
    int s, unsigned wp, int nval, int lane, int shamt, float& acc0, float& acc1){
  for(int e = 0; e < nval; e += 8){
    unsigned v[8]; float w[8];
    #pragma unroll
    for(int u=0;u<8;u++){
      int se       = __shfl(s,  e+u);
      unsigned wpe = __shfl(wp, e+u);
      w[u] = __uint_as_float((wpe << shamt) & 0xffff0000u);
      v[u] = featb[((unsigned)se << 6) + (unsigned)lane];
    }
    #pragma unroll
    for(int u=0;u<8;u++){
      acc0 += bf_lo(v[u]) * w[u];
      acc1 += bf_hi(v[u]) * w[u];
    }
  }
}

// ---------------- GAT aggregation: wave per dst node, bf16 gather -> bf16 out
__global__ __launch_bounds__(256) void agg_kernel(const unsigned* __restrict__ featb,
    const float* __restrict__ el, const float* __restrict__ er,
    const int* __restrict__ rowptr, const int* __restrict__ esrc,
    const float* __restrict__ bias, unsigned* __restrict__ outp, int n){
  int wid = (blockIdx.x*blockDim.x + threadIdx.x) >> 6;
  int lane = threadIdx.x & 63;
  if(wid >= n) return;
  int beg = rowptr[wid], end = rowptr[wid+1];
  int deg = end - beg;
  float2 erd = *(const float2*)&er[(size_t)wid*2];
  int shamt = (lane < 32) ? 16 : 0;
  float acc0 = 0.f, acc1 = 0.f;

  if(deg <= 64){
    int s = (lane < deg) ? esrc[beg + lane] : 0;
    float2 elv = *(const float2*)&el[(size_t)s*2];
    float e0 = elv.x + erd.x, e1 = elv.y + erd.y;
    e0 = (e0 >= 0.f) ? e0 : SLOPE*e0;
    e1 = (e1 >= 0.f) ? e1 : SLOPE*e1;
    float p0 = __expf(e0), p1 = __expf(e1);
    if(lane >= deg){ p0 = 0.f; p1 = 0.f; }
    float d0 = wave_sum(p0), d1 = wave_sum(p1);
    unsigned wp = pack_bf16(p0 / fmaxf(d0, 1e-16f), p1 / fmaxf(d1, 1e-16f));
    agg_chunk(featb, s, wp, deg, lane, shamt, acc0, acc1);
  } else {
    float d0 = 0.f, d1 = 0.f;
    for(int base = beg; base < end; base += 64){
      int idx = base + lane;
      int s = (idx < end) ? esrc[idx] : 0;
      float2 elv = *(const float2*)&el[(size_t)s*2];
      float e0 = elv.x + erd.x, e1 = elv.y + erd.y;
      e0 = (e0 >= 0.f) ? e0 : SLOPE*e0;
      e1 = (e1 >= 0.f) ? e1 : SLOPE*e1;
      float p0 = __expf(e0), p1 = __expf(e1);
      if(idx >= end){ p0 = 0.f; p1 = 0.f; }
      d0 += p0; d1 += p1;
    }
    d0 = wave_sum(d0); d1 = wave_sum(d1);
    float inv0 = 1.0f / fmaxf(d0, 1e-16f);
    float inv1 = 1.0f / fmaxf(d1, 1e-16f);
    for(int base = beg; base < end; base += 64){
      int idx = base + lane;
      int s = (idx < end) ? esrc[idx] : 0;
      float2 elv = *(const float2*)&el[(size_t)s*2];
      float e0 = elv.x + erd.x, e1 = elv.y + erd.y;
      e0 = (e0 >= 0.f) ? e0 : SLOPE*e0;
      e1 = (e1 >= 0.f) ? e1 : SLOPE*e1;
      unsigned wp = pack_bf16(__expf(e0) * inv0, __expf(e1) * inv1);
      if(idx >= end) wp = 0;
      agg_chunk(featb, s, wp, min(64, end - base), lane, shamt, acc0, acc1);
    }
  }
  float2 bb = *(const float2*)&bias[2*lane];
  outp[(size_t)wid*64 + lane] =
      pack_bf16(fmaxf(acc0 + bb.x, 0.f), fmaxf(acc1 + bb.y, 0.f));
}

// ---------------- head: relu(h@Wout+bout) @ Wfc + bfc   (h is bf16-packed)
__global__ __launch_bounds__(256) void head_kernel(const unsigned* __restrict__ h,
    const float* __restrict__ Wout, const float* __restrict__ bout,
    const float* __restrict__ Wfc, const float* __restrict__ bfc,
    float* __restrict__ hfc, int n){
  __shared__ float sAT[32][68];
  __shared__ float sWo[32][68];
  __shared__ float sOT[64][68];
  __shared__ float sF [64][68];
  int t = threadIdx.x;
  int cx = t & 15;
  int ry = t >> 4;
  int row0 = blockIdx.x * 64;

  {
    int kr = t >> 4;
    int c0 = (t & 15) * 4;
    #pragma unroll
    for(int i=0;i<4;i++)
      *(float4*)&sF[kr+i*16][c0] = *(const float4*)&Wfc[(size_t)(kr+i*16)*64 + c0];
  }

  float acc[4][4] = {};
  for(int k0 = 0; k0 < 128; k0 += 32){
    #pragma unroll
    for(int u=0;u<2;u++){
      int f4 = t*2 + u;
      int r  = f4 >> 3;
      int kc = (f4 & 7) * 4;
      int gr = row0 + r;
      uint2 v = make_uint2(0,0);
      if(gr < n) v = *(const uint2*)&h[(size_t)gr*64 + ((k0+kc)>>1)];
      sAT[kc+0][r] = bf_lo(v.x);
      sAT[kc+1][r] = bf_hi(v.x);
      sAT[kc+2][r] = bf_lo(v.y);
      sAT[kc+3][r] = bf_hi(v.y);
    }
    #pragma unroll
    for(int u=0;u<2;u++){
      int f4 = t*2 + u;
      int kr = f4 >> 4;
      int c0 = (f4 & 15) * 4;
      *(float4*)&sWo[kr][c0] = *(const float4*)&Wout[(size_t)(k0+kr)*64 + c0];
    }
    __syncthreads();
    #pragma unroll 8
    for(int kk = 0; kk < 32; ++kk){
      float4 a4 = *(const float4*)&sAT[kk][ry*4];
      float4 b4 = *(const float4*)&sWo[kk][cx*4];
      float a[4] = {a4.x,a4.y,a4.z,a4.w};
      float b[4] = {b4.x,b4.y,b4.z,b4.w};
      #pragma unroll
      for(int i=0;i<4;i++)
        #pragma unroll
        for(int j=0;j<4;j++) acc[i][j] += a[i]*b[j];
    }
    __syncthreads();
  }
  {
    float4 bb = *(const float4*)&bout[cx*4];
    float bv[4] = {bb.x,bb.y,bb.z,bb.w};
    #pragma unroll
    for(int i=0;i<4;i++)
      #pragma unroll
      for(int j=0;j<4;j++)
        sOT[cx*4+j][ry*4+i] = fmaxf(acc[i][j] + bv[j], 0.f);
  }
  __syncthreads();
  float acc2[4][4] = {};
  #pragma unroll 8
  for(int kk = 0; kk < 64; ++kk){
    float4 a4 = *(const float4*)&sOT[kk][ry*4];
    float4 b4 = *(const float4*)&sF [kk][cx*4];
    float a[4] = {a4.x,a4.y,a4.z,a4.w};
    float b[4] = {b4.x,b4.y,b4.z,b4.w};
    #pragma unroll
    for(int i=0;i<4;i++)
      #pragma unroll
      for(int j=0;j<4;j++) acc2[i][j] += a[i]*b[j];
  }
  {
    float4 bb = *(const float4*)&bfc[cx*4];
    #pragma unroll
    for(int i=0;i<4;i++){
      int gr = row0 + ry*4 + i;
      if(gr < n){
        float4 o = make_float4(acc2[i][0]+bb.x, acc2[i][1]+bb.y,
                               acc2[i][2]+bb.z, acc2[i][3]+bb.w);
        *(float4*)&hfc[(size_t)gr*64 + cx*4] = o;
      }
    }
  }
}

// ---------------- BN stats (two-stage, deterministic)
__global__ __launch_bounds__(256) void bn_stats(const float* __restrict__ hfc,
    float* __restrict__ psum, float* __restrict__ psum2, int n){
  int t = threadIdx.x; int c = t & 63; int g = t >> 6;
  int rpb = (n + gridDim.x - 1) / gridDim.x;
  int r0 = blockIdx.x * rpb;
  int r1 = min(n, r0 + rpb);
  float s = 0.f, s2 = 0.f;
  for(int r = r0 + g; r < r1; r += 4){
    float v = hfc[(size_t)r*64 + c];
    s += v; s2 += v*v;
  }
  __shared__ float ls[256], ls2[256];
  ls[t]=s; ls2[t]=s2; __syncthreads();
  if(t < 64){
    s  = ls[t]+ls[t+64]+ls[t+128]+ls[t+192];
    s2 = ls2[t]+ls2[t+64]+ls2[t+128]+ls2[t+192];
    psum[blockIdx.x*64 + t]  = s;
    psum2[blockIdx.x*64 + t] = s2;
  }
}

__global__ __launch_bounds__(64) void bn_fin(const float* __restrict__ psum,
    const float* __restrict__ psum2, const float* __restrict__ gamma,
    const float* __restrict__ beta, float* __restrict__ scsh, int n, int nb){
  int c = threadIdx.x;
  float s=0.f, s2=0.f;
  for(int b=0;b<nb;b++){ s += psum[b*64+c]; s2 += psum2[b*64+c]; }
  float mu  = s / n;
  float var = s2 / n - mu*mu;
  float scale = rsqrtf(var + BN_EPS) * gamma[c];
  scsh[c]    = scale;
  scsh[64+c] = beta[c] - mu*scale;
}

// ---------------- BN apply + row softmax -> p
__global__ __launch_bounds__(256) void bn_softmax(const float* __restrict__ hfc,
    const float* __restrict__ scsh, float* __restrict__ p, int n){
  int wid = (blockIdx.x*blockDim.x + threadIdx.x) >> 6;
  int lane = threadIdx.x & 63;
  if(wid >= n) return;
  float y = hfc[(size_t)wid*64 + lane]*scsh[lane] + scsh[64+lane];
  float m = wave_max(y);
  float e = expf(y - m);
  float s = wave_sum(e);
  p[(size_t)wid*64 + lane] = e / s;
}

// ---------------- loss
__global__ __launch_bounds__(256) void loss1(const float* __restrict__ p,
    const int* __restrict__ train, const int* __restrict__ label,
    float* __restrict__ part, int ntrain){
  int lane = threadIdx.x & 63; int w = threadIdx.x >> 6;
  int gw = blockIdx.x*4 + w; int nw = gridDim.x*4;
  float acc = 0.f;
  for(int t = gw; t < ntrain; t += nw){
    int node = train[t];
    float v = p[(size_t)node*64 + lane];
    float m = wave_max(v);
    float e = expf(v - m);
    float s = wave_sum(e);
    float logp = (v - m) - logf(s);
    int lab = label[node];
    if(lane == lab) acc += logp;
  }
  acc = wave_sum(acc);
  __shared__ float ls[4];
  if(lane == 0) ls[w] = acc;
  __syncthreads();
  if(threadIdx.x == 0) part[blockIdx.x] = ls[0]+ls[1]+ls[2]+ls[3];
}

__global__ void loss2(const float* __restrict__ part, float* __restrict__ out,
                      int nb, int ntrain){
  if(threadIdx.x == 0){
    float s = 0.f;
    for(int i=0;i<nb;i++) s += part[i];
    out[0] = -s / (float)ntrain;
  }
}

extern "C" void kernel_launch(void* const* d_in, const int* in_sizes, int n_in,
                              void* d_out, int out_size, void* d_ws, size_t ws_size,
                              hipStream_t stream){
  const float* feature = (const float*)d_in[0];
  const int*   label   = (const int*)d_in[1];
  const int*   train   = (const int*)d_in[2];
  const int*   src     = (const int*)d_in[3];
  const int*   dst     = (const int*)d_in[4];
  const float* W0   = (const float*)d_in[5];
  const float* al0  = (const float*)d_in[6];
  const float* ar0  = (const float*)d_in[7];
  const float* b0   = (const float*)d_in[8];
  const float* W1   = (const float*)d_in[9];
  const float* al1  = (const float*)d_in[10];
  const float* ar1  = (const float*)d_in[11];
  const float* b1   = (const float*)d_in[12];
  const float* Wout = (const float*)d_in[13];
  const float* bout = (const float*)d_in[14];
  const float* Wfc  = (const float*)d_in[15];
  const float* bfc  = (const float*)d_in[16];
  const float* gamma= (const float*)d_in[17];
  const float* beta = (const float*)d_in[18];

  const int N  = in_sizes[1];
  const int NT = in_sizes[2];
  const int E  = in_sizes[3];

  const int nbuck  = (N + (1<<NBUCK_SH) - 1) >> NBUCK_SH;
  const int ntiles = (E + CSR_TILE - 1) / CSR_TILE;

  size_t off = 0;
  auto alloc = [&](size_t bytes)->void*{
    void* pp = (char*)d_ws + off;
    off += (bytes + 255) & ~(size_t)255;
    return pp;
  };
  unsigned* featb16 = (unsigned*)alloc((size_t)N*64*4);
  unsigned* hbuf2   = (unsigned*)alloc((size_t)N*64*4);
  float* el      = (float*)alloc((size_t)N*2*4);
  float* er      = (float*)alloc((size_t)N*2*4);
  int*   rowptr  = (int*)alloc((size_t)(N+1)*4);
  int*   esrc    = (int*)alloc((size_t)E*4);
  int*   thist   = (int*)alloc((size_t)ntiles*nbuck*4);
  int*   offarr  = (int*)alloc((size_t)nbuck*ntiles*4);
  int*   btotal  = (int*)alloc((size_t)nbuck*4);
  int*   bbase   = (int*)alloc((size_t)(nbuck+1)*4);
  unsigned* Wt0  = (unsigned*)alloc((size_t)128*128*4);
  unsigned* Wt1  = (unsigned*)alloc((size_t)128*64*4);
  float* psum    = (float*)alloc((size_t)256*64*4);
  float* psum2   = (float*)alloc((size_t)256*64*4);
  float* scsh    = (float*)alloc(128*4);
  float* lpart   = (float*)alloc(256*4);
  float* hfc     = (float*)featb16;
  unsigned* tmp  = hbuf2;

  float* p_out   = (float*)d_out;
  float* loss_out= (float*)d_out + (size_t)N*64;

  const int nwaveblk = (N + 3) / 4;

  // ---- weight prep (bf16, transposed) — single launch
  wtrans2<<<96, 256, 0, stream>>>(W0, W1, Wt0, Wt1);

  // ---- CSR build (two-level counting sort)
  csrA<<<ntiles, 256, 0, stream>>>(dst, thist, E, nbuck, ntiles);
  csrB1<<<nbuck, 512, 0, stream>>>(thist, offarr, btotal, nbuck, ntiles);
  csrB2<<<1, 256, 0, stream>>>(btotal, bbase, nbuck, E);
  csrC<<<ntiles, 256, 0, stream>>>(src, dst, offarr, bbase, tmp, E, nbuck, ntiles);
  csrD<<<nbuck, 512, 0, stream>>>(tmp, bbase, rowptr, esrc, N, E, nbuck);

  // ---- layer 0 (gemm fuses el/er epilogue)
  gemm_mfma<1><<<(N+127)/128, 256, 0, stream>>>(feature, Wt0, featb16, al0, ar0, el, er, N, 256);
  agg_kernel<<<nwaveblk, 256, 0, stream>>>(featb16, el, er, rowptr, esrc, b0, hbuf2, N);

  // ---- layer 1
  gemm_mfma<0><<<(N+127)/128, 256, 0, stream>>>(hbuf2, Wt1, featb16, al1, ar1, el, er, N, 128);
  agg_kernel<<<nwaveblk, 256, 0, stream>>>(featb16, el, er, rowptr, esrc, b1, hbuf2, N);

  // ---- dense head
  head_kernel<<<(N+63)/64, 256, 0, stream>>>(hbuf2, Wout, bout, Wfc, bfc, hfc, N);

  // ---- batchnorm
  bn_stats<<<256, 256, 0, stream>>>(hfc, psum, psum2, N);
  bn_fin<<<1, 64, 0, stream>>>(psum, psum2, gamma, beta, scsh, N, 256);
  bn_softmax<<<nwaveblk, 256, 0, stream>>>(hfc, scsh, p_out, N);

  // ---- loss
  loss1<<<40, 256, 0, stream>>>(p_out, train, label, lpart, NT);
  loss2<<<1, 64, 0, stream>>>(lpart, loss_out, 40, NT);
}

// Round 12
// 456.221 us; speedup vs baseline: 1.0097x; 1.0097x over previous
//
#include <hip/hip_runtime.h>

#define SLOPE 0.2f
#define BN_EPS 1e-5f

#define CSR_TILE 4096       // edges per tile
#define NBUCK_SH 9          // bucket = dst >> 9  (512 nodes per bucket)
#define BCAP 16384          // per-bucket slab capacity in tmp (E/nbuck ~8.2K, 2x slack)

typedef __attribute__((ext_vector_type(8))) short bf16x8;
typedef __attribute__((ext_vector_type(4))) float f32x4;

__device__ __forceinline__ float wave_sum(float v){
  #pragma unroll
  for(int o=32;o;o>>=1) v += __shfl_xor(v,o);
  return v;
}
__device__ __forceinline__ float wave_max(float v){
  #pragma unroll
  for(int o=32;o;o>>=1) v = fmaxf(v,__shfl_xor(v,o));
  return v;
}
__device__ __forceinline__ unsigned pack_bf16(float a, float b){
  unsigned ua=__float_as_uint(a), ub=__float_as_uint(b);
  ua += 0x7fffu + ((ua>>16)&1u);
  ub += 0x7fffu + ((ub>>16)&1u);
  return (ua>>16) | (ub & 0xffff0000u);
}
__device__ __forceinline__ float bf_lo(unsigned u){ return __uint_as_float(u<<16); }
__device__ __forceinline__ float bf_hi(unsigned u){ return __uint_as_float(u & 0xffff0000u); }

// ---------------- both weight transposes in one launch
__global__ __launch_bounds__(256) void wtrans2(const float* __restrict__ W0,
    const float* __restrict__ W1, unsigned* __restrict__ Wt0, unsigned* __restrict__ Wt1){
  int idx = blockIdx.x*256 + threadIdx.x;
  if(blockIdx.x < 64){
    int c = idx >> 7, kp = idx & 127;          // W0: K=256 -> 128 kpairs
    Wt0[(size_t)c*128 + kp] = pack_bf16(W0[(size_t)(2*kp)*128 + c], W0[(size_t)(2*kp+1)*128 + c]);
  } else {
    int i2 = idx - 64*256;
    int c = i2 >> 6, kp = i2 & 63;             // W1: K=128 -> 64 kpairs
    Wt1[(size_t)c*64 + kp] = pack_bf16(W1[(size_t)(2*kp)*128 + c], W1[(size_t)(2*kp+1)*128 + c]);
  }
}

// ---------------- MFMA GEMM: A[n,K] @ W[K,128] -> bf16-packed out[n][64 uints]
// 128x128 tile, 4 waves (64x64 quadrant, 4x4 frags). A: LDS (reg-prefetch).
// B: registers straight from L2-resident Wt. Direct-scatter epilogue + fused el/er.
template<int AF32>
__global__ __launch_bounds__(256) void gemm_mfma(const void* __restrict__ Aptr,
    const unsigned* __restrict__ Wt, unsigned* __restrict__ outb,
    const float* __restrict__ al, const float* __restrict__ ar,
    float* __restrict__ el, float* __restrict__ er, int n, int K){
  __shared__ unsigned sA[128][36];     // 18.4 KB, [row][kpair] +16B pad
  int t = threadIdx.x;
  int w = t >> 6, l = t & 63;
  int wr = (w >> 1) * 64, wc = (w & 1) * 64;
  int row0 = blockIdx.x * 128;
  int K2 = K >> 1;
  int ktiles = K >> 6;

  int srow[4], sslot[4];
  #pragma unroll
  for(int i=0;i<4;i++){ int u4 = t + i*256; srow[i] = u4>>3; sslot[i] = u4&7; }

  uint4 pa[4][2];

  auto load_tile = [&](int kt){
    if(AF32){
      const float* A = (const float*)Aptr;
      #pragma unroll
      for(int i=0;i<4;i++){
        int gr = row0 + srow[i];
        pa[i][0] = make_uint4(0,0,0,0);
        pa[i][1] = make_uint4(0,0,0,0);
        if(gr < n){
          const unsigned* ap = (const unsigned*)(A + (size_t)gr*K + kt*64 + sslot[i]*8);
          pa[i][0] = *(const uint4*)ap;
          pa[i][1] = *(const uint4*)(ap+4);
        }
      }
    } else {
      const unsigned* A = (const unsigned*)Aptr;
      #pragma unroll
      for(int i=0;i<4;i++){
        int gr = row0 + srow[i];
        pa[i][0] = make_uint4(0,0,0,0);
        if(gr < n) pa[i][0] = *(const uint4*)(A + (size_t)gr*K2 + kt*32 + sslot[i]*4);
      }
    }
  };

  auto store_tile = [&](){
    if(AF32){
      #pragma unroll
      for(int i=0;i<4;i++){
        uint4 v;
        v.x = pack_bf16(__uint_as_float(pa[i][0].x), __uint_as_float(pa[i][0].y));
        v.y = pack_bf16(__uint_as_float(pa[i][0].z), __uint_as_float(pa[i][0].w));
        v.z = pack_bf16(__uint_as_float(pa[i][1].x), __uint_as_float(pa[i][1].y));
        v.w = pack_bf16(__uint_as_float(pa[i][1].z), __uint_as_float(pa[i][1].w));
        *(uint4*)&sA[srow[i]][sslot[i]*4] = v;
      }
    } else {
      #pragma unroll
      for(int i=0;i<4;i++)
        *(uint4*)&sA[srow[i]][sslot[i]*4] = pa[i][0];
    }
  };

  f32x4 zero4 = {0.f,0.f,0.f,0.f};
  f32x4 acc[4][4];
  #pragma unroll
  for(int i=0;i<4;i++)
    #pragma unroll
    for(int j=0;j<4;j++) acc[i][j] = zero4;

  int rl = l & 15;
  load_tile(0);
  for(int kt = 0; kt < ktiles; ++kt){
    store_tile();
    __syncthreads();
    if(kt+1 < ktiles) load_tile(kt+1);   // A prefetch in flight during MFMA
    #pragma unroll
    for(int ks=0; ks<2; ++ks){
      int koff = ks*16 + (l>>4)*4;
      bf16x8 a[4], b[4];
      #pragma unroll
      for(int f=0; f<4; f++)
        b[f] = *(const bf16x8*)&Wt[(size_t)(wc + f*16 + rl)*K2 + kt*32 + koff];
      #pragma unroll
      for(int f=0; f<4; f++)
        a[f] = *(const bf16x8*)&sA[wr + f*16 + rl][koff];
      #pragma unroll
      for(int i=0;i<4;i++)
        #pragma unroll
        for(int j=0;j<4;j++)
          acc[i][j] = __builtin_amdgcn_mfma_f32_16x16x32_bf16(a[i], b[j], acc[i][j], 0, 0, 0);
    }
    __syncthreads();
  }

  // C-write (direct scatter, round-8 proven): col=lane&15, row=(lane>>4)*4+reg
  #pragma unroll
  for(int i=0;i<4;i++){
    #pragma unroll
    for(int j=0;j<4;j++){
      #pragma unroll
      for(int g=0;g<4;g++){
        float v  = acc[i][j][g];
        float vp = __shfl_xor(v, 1);
        if(!(l & 1)){
          unsigned pv = pack_bf16(v, vp);
          int grow = row0 + wr + i*16 + (l>>4)*4 + g;
          int gcol = wc + j*16 + (l&15);
          if(grow < n) outb[(size_t)grow*64 + (gcol>>1)] = pv;
        }
      }
    }
  }

  // fused el/er: wave covers head h = wc>>6 for rows wr..wr+63
  {
    int h = wc >> 6;
    float alv[4], arv[4];
    #pragma unroll
    for(int j=0;j<4;j++){
      int c = wc + j*16 + (l&15);
      alv[j] = al[c]; arv[j] = ar[c];
    }
    #pragma unroll
    for(int i=0;i<4;i++){
      #pragma unroll
      for(int g=0;g<4;g++){
        float pe = acc[i][0][g]*alv[0] + acc[i][1][g]*alv[1]
                 + acc[i][2][g]*alv[2] + acc[i][3][g]*alv[3];
        float qe = acc[i][0][g]*arv[0] + acc[i][1][g]*arv[1]
                 + acc[i][2][g]*arv[2] + acc[i][3][g]*arv[3];
        #pragma unroll
        for(int o=8;o;o>>=1){ pe += __shfl_xor(pe,o); qe += __shfl_xor(qe,o); }
        if((l & 15) == 0){
          int grow = row0 + wr + i*16 + (l>>4)*4 + g;
          if(grow < n){
            el[(size_t)grow*2 + h] = pe;
            er[(size_t)grow*2 + h] = qe;
          }
        }
      }
    }
  }
}

// ================= CSR build: fused counting sort =================
// One pass: tile edges cached in LDS, per-tile hist, global range reservation,
// scatter into per-bucket slabs tmp[b*BCAP ..]. cursor[] must be zeroed first.
__global__ __launch_bounds__(256) void csrABC(const int* __restrict__ src,
    const int* __restrict__ dst, int* __restrict__ cursor,
    unsigned* __restrict__ tmp, int E, int nbuck){
  __shared__ unsigned eb[CSR_TILE];   // packed (dl<<17 | s)  16KB
  __shared__ short    ebb[CSR_TILE];  // bucket per edge       8KB
  __shared__ int hist[256];
  __shared__ int basel[256];
  int t = threadIdx.x;
  hist[t] = 0;
  __syncthreads();
  int base = blockIdx.x * CSR_TILE;
  int cnt  = min(CSR_TILE, E - base);
  for(int k = t; k < cnt; k += 256){
    int d = dst[base + k];
    int s = src[base + k];
    int b = d >> NBUCK_SH;
    eb[k]  = (unsigned)s | ((unsigned)(d & ((1<<NBUCK_SH)-1)) << 17);
    ebb[k] = (short)b;
    atomicAdd(&hist[b], 1);
  }
  __syncthreads();
  if(t < nbuck && hist[t] > 0)
    basel[t] = atomicAdd(&cursor[t], hist[t]);   // reserve range in bucket slab
  __syncthreads();
  hist[t] = 0;                                    // reuse as running cnt
  __syncthreads();
  for(int k = t; k < cnt; k += 256){
    int b = ebb[k];
    int r = atomicAdd(&hist[b], 1);
    tmp[(size_t)b*BCAP + basel[b] + r] = eb[k];
  }
}

// scan bucket counts (=cursor) -> bbase
__global__ __launch_bounds__(256) void scanB(const int* __restrict__ cursor,
    int* __restrict__ bbase, int nbuck, int E){
  __shared__ int ls[256];
  int t = threadIdx.x;
  int v = (t < nbuck) ? cursor[t] : 0;
  ls[t] = v; __syncthreads();
  for(int o=1;o<256;o<<=1){
    int x = (t>=o) ? ls[t-o] : 0;
    __syncthreads();
    ls[t] += x;
    __syncthreads();
  }
  if(t < nbuck) bbase[t] = ls[t] - v;
  if(t == 0) bbase[nbuck] = E;
}

// per bucket: local hist+scan -> rowptr, scatter src ids -> esrc
__global__ __launch_bounds__(512) void csrD(const unsigned* __restrict__ tmp,
    const int* __restrict__ bbase, int* __restrict__ rowptr,
    int* __restrict__ esrc, int N, int E, int nbuck){
  __shared__ int hist[512];
  __shared__ int ls[512];
  int t = threadIdx.x;
  int b = blockIdx.x;
  int base = bbase[b];
  int cnt  = bbase[b+1] - base;
  const unsigned* tp = tmp + (size_t)b*BCAP;
  int n0   = b << NBUCK_SH;
  int nn   = min(512, N - n0);
  hist[t] = 0;
  __syncthreads();
  for(int i = t; i < cnt; i += 512)
    atomicAdd(&hist[tp[i] >> 17], 1);
  __syncthreads();
  int v = hist[t];
  ls[t] = v; __syncthreads();
  for(int o=1;o<512;o<<=1){
    int x = (t>=o) ? ls[t-o] : 0;
    __syncthreads();
    ls[t] += x;
    __syncthreads();
  }
  int rp = ls[t] - v;
  if(t < nn) rowptr[n0 + t] = base + rp;
  if(b == nbuck-1 && t == 0) rowptr[N] = E;
  __syncthreads();
  hist[t] = rp;
  __syncthreads();
  for(int i = t; i < cnt; i += 512){
    unsigned v2 = tp[i];
    int dl = v2 >> 17;
    int s  = v2 & 0x1FFFF;
    int r  = atomicAdd(&hist[dl], 1);
    esrc[base + r] = s;
  }
}

// ---- 8-deep gather/accumulate over one ≤64-edge chunk; zero-weight lanes pad the tail
__device__ __forceinline__ void agg_chunk(const unsigned* __restrict__ featb,
    int s, unsigned wp, int nval, int lane, int shamt, float& acc0, float& acc1){
  for(int e = 0; e < nval; e += 8){
    unsigned v[8]; float w[8];
    #pragma unroll
    for(int u=0;u<8;u++){
      int se       = __shfl(s,  e+u);
      unsigned wpe = __shfl(wp, e+u);
      w[u] = __uint_as_float((wpe << shamt) & 0xffff0000u);
      v[u] = featb[((unsigned)se << 6) + (unsigned)lane];
    }
    #pragma unroll
    for(int u=0;u<8;u++){
      acc0 += bf_lo(v[u]) * w[u];
      acc1 += bf_hi(v[u]) * w[u];
    }
  }
}

// ---------------- GAT aggregation: wave per dst node, bf16 gather -> bf16 out
__global__ __launch_bounds__(256) void agg_kernel(const unsigned* __restrict__ featb,
    const float* __restrict__ el, const float* __restrict__ er,
    const int* __restrict__ rowptr, const int* __restrict__ esrc,
    const float* __restrict__ bias, unsigned* __restrict__ outp, int n){
  int wid = (blockIdx.x*blockDim.x + threadIdx.x) >> 6;
  int lane = threadIdx.x & 63;
  if(wid >= n) return;
  int beg = rowptr[wid], end = rowptr[wid+1];
  int deg = end - beg;
  float2 erd = *(const float2*)&er[(size_t)wid*2];
  int shamt = (lane < 32) ? 16 : 0;
  float acc0 = 0.f, acc1 = 0.f;

  if(deg <= 64){
    int s = (lane < deg) ? esrc[beg + lane] : 0;
    float2 elv = *(const float2*)&el[(size_t)s*2];
    float e0 = elv.x + erd.x, e1 = elv.y + erd.y;
    e0 = (e0 >= 0.f) ? e0 : SLOPE*e0;
    e1 = (e1 >= 0.f) ? e1 : SLOPE*e1;
    float p0 = __expf(e0), p1 = __expf(e1);
    if(lane >= deg){ p0 = 0.f; p1 = 0.f; }
    float d0 = wave_sum(p0), d1 = wave_sum(p1);
    unsigned wp = pack_bf16(p0 / fmaxf(d0, 1e-16f), p1 / fmaxf(d1, 1e-16f));
    agg_chunk(featb, s, wp, deg, lane, shamt, acc0, acc1);
  } else {
    float d0 = 0.f, d1 = 0.f;
    for(int base = beg; base < end; base += 64){
      int idx = base + lane;
      int s = (idx < end) ? esrc[idx] : 0;
      float2 elv = *(const float2*)&el[(size_t)s*2];
      float e0 = elv.x + erd.x, e1 = elv.y + erd.y;
      e0 = (e0 >= 0.f) ? e0 : SLOPE*e0;
      e1 = (e1 >= 0.f) ? e1 : SLOPE*e1;
      float p0 = __expf(e0), p1 = __expf(e1);
      if(idx >= end){ p0 = 0.f; p1 = 0.f; }
      d0 += p0; d1 += p1;
    }
    d0 = wave_sum(d0); d1 = wave_sum(d1);
    float inv0 = 1.0f / fmaxf(d0, 1e-16f);
    float inv1 = 1.0f / fmaxf(d1, 1e-16f);
    for(int base = beg; base < end; base += 64){
      int idx = base + lane;
      int s = (idx < end) ? esrc[idx] : 0;
      float2 elv = *(const float2*)&el[(size_t)s*2];
      float e0 = elv.x + erd.x, e1 = elv.y + erd.y;
      e0 = (e0 >= 0.f) ? e0 : SLOPE*e0;
      e1 = (e1 >= 0.f) ? e1 : SLOPE*e1;
      unsigned wp = pack_bf16(__expf(e0) * inv0, __expf(e1) * inv1);
      if(idx >= end) wp = 0;
      agg_chunk(featb, s, wp, min(64, end - base), lane, shamt, acc0, acc1);
    }
  }
  float2 bb = *(const float2*)&bias[2*lane];
  outp[(size_t)wid*64 + lane] =
      pack_bf16(fmaxf(acc0 + bb.x, 0.f), fmaxf(acc1 + bb.y, 0.f));
}

// ---------------- head: relu(h@Wout+bout) @ Wfc + bfc   (h is bf16-packed)
__global__ __launch_bounds__(256) void head_kernel(const unsigned* __restrict__ h,
    const float* __restrict__ Wout, const float* __restrict__ bout,
    const float* __restrict__ Wfc, const float* __restrict__ bfc,
    float* __restrict__ hfc, int n){
  __shared__ float sAT[32][68];
  __shared__ float sWo[32][68];
  __shared__ float sOT[64][68];
  __shared__ float sF [64][68];
  int t = threadIdx.x;
  int cx = t & 15;
  int ry = t >> 4;
  int row0 = blockIdx.x * 64;

  {
    int kr = t >> 4;
    int c0 = (t & 15) * 4;
    #pragma unroll
    for(int i=0;i<4;i++)
      *(float4*)&sF[kr+i*16][c0] = *(const float4*)&Wfc[(size_t)(kr+i*16)*64 + c0];
  }

  float acc[4][4] = {};
  for(int k0 = 0; k0 < 128; k0 += 32){
    #pragma unroll
    for(int u=0;u<2;u++){
      int f4 = t*2 + u;
      int r  = f4 >> 3;
      int kc = (f4 & 7) * 4;
      int gr = row0 + r;
      uint2 v = make_uint2(0,0);
      if(gr < n) v = *(const uint2*)&h[(size_t)gr*64 + ((k0+kc)>>1)];
      sAT[kc+0][r] = bf_lo(v.x);
      sAT[kc+1][r] = bf_hi(v.x);
      sAT[kc+2][r] = bf_lo(v.y);
      sAT[kc+3][r] = bf_hi(v.y);
    }
    #pragma unroll
    for(int u=0;u<2;u++){
      int f4 = t*2 + u;
      int kr = f4 >> 4;
      int c0 = (f4 & 15) * 4;
      *(float4*)&sWo[kr][c0] = *(const float4*)&Wout[(size_t)(k0+kr)*64 + c0];
    }
    __syncthreads();
    #pragma unroll 8
    for(int kk = 0; kk < 32; ++kk){
      float4 a4 = *(const float4*)&sAT[kk][ry*4];
      float4 b4 = *(const float4*)&sWo[kk][cx*4];
      float a[4] = {a4.x,a4.y,a4.z,a4.w};
      float b[4] = {b4.x,b4.y,b4.z,b4.w};
      #pragma unroll
      for(int i=0;i<4;i++)
        #pragma unroll
        for(int j=0;j<4;j++) acc[i][j] += a[i]*b[j];
    }
    __syncthreads();
  }
  {
    float4 bb = *(const float4*)&bout[cx*4];
    float bv[4] = {bb.x,bb.y,bb.z,bb.w};
    #pragma unroll
    for(int i=0;i<4;i++)
      #pragma unroll
      for(int j=0;j<4;j++)
        sOT[cx*4+j][ry*4+i] = fmaxf(acc[i][j] + bv[j], 0.f);
  }
  __syncthreads();
  float acc2[4][4] = {};
  #pragma unroll 8
  for(int kk = 0; kk < 64; ++kk){
    float4 a4 = *(const float4*)&sOT[kk][ry*4];
    float4 b4 = *(const float4*)&sF [kk][cx*4];
    float a[4] = {a4.x,a4.y,a4.z,a4.w};
    float b[4] = {b4.x,b4.y,b4.z,b4.w};
    #pragma unroll
    for(int i=0;i<4;i++)
      #pragma unroll
      for(int j=0;j<4;j++) acc2[i][j] += a[i]*b[j];
  }
  {
    float4 bb = *(const float4*)&bfc[cx*4];
    #pragma unroll
    for(int i=0;i<4;i++){
      int gr = row0 + ry*4 + i;
      if(gr < n){
        float4 o = make_float4(acc2[i][0]+bb.x, acc2[i][1]+bb.y,
                               acc2[i][2]+bb.z, acc2[i][3]+bb.w);
        *(float4*)&hfc[(size_t)gr*64 + cx*4] = o;
      }
    }
  }
}

// ---------------- BN stats (two-stage, deterministic)
__global__ __launch_bounds__(256) void bn_stats(const float* __restrict__ hfc,
    float* __restrict__ psum, float* __restrict__ psum2, int n){
  int t = threadIdx.x; int c = t & 63; int g = t >> 6;
  int rpb = (n + gridDim.x - 1) / gridDim.x;
  int r0 = blockIdx.x * rpb;
  int r1 = min(n, r0 + rpb);
  float s = 0.f, s2 = 0.f;
  for(int r = r0 + g; r < r1; r += 4){
    float v = hfc[(size_t)r*64 + c];
    s += v; s2 += v*v;
  }
  __shared__ float ls[256], ls2[256];
  ls[t]=s; ls2[t]=s2; __syncthreads();
  if(t < 64){
    s  = ls[t]+ls[t+64]+ls[t+128]+ls[t+192];
    s2 = ls2[t]+ls2[t+64]+ls2[t+128]+ls2[t+192];
    psum[blockIdx.x*64 + t]  = s;
    psum2[blockIdx.x*64 + t] = s2;
  }
}

__global__ __launch_bounds__(64) void bn_fin(const float* __restrict__ psum,
    const float* __restrict__ psum2, const float* __restrict__ gamma,
    const float* __restrict__ beta, float* __restrict__ scsh, int n, int nb){
  int c = threadIdx.x;
  float s=0.f, s2=0.f;
  for(int b=0;b<nb;b++){ s += psum[b*64+c]; s2 += psum2[b*64+c]; }
  float mu  = s / n;
  float var = s2 / n - mu*mu;
  float scale = rsqrtf(var + BN_EPS) * gamma[c];
  scsh[c]    = scale;
  scsh[64+c] = beta[c] - mu*scale;
}

// ---------------- BN apply + row softmax -> p
__global__ __launch_bounds__(256) void bn_softmax(const float* __restrict__ hfc,
    const float* __restrict__ scsh, float* __restrict__ p, int n){
  int wid = (blockIdx.x*blockDim.x + threadIdx.x) >> 6;
  int lane = threadIdx.x & 63;
  if(wid >= n) return;
  float y = hfc[(size_t)wid*64 + lane]*scsh[lane] + scsh[64+lane];
  float m = wave_max(y);
  float e = expf(y - m);
  float s = wave_sum(e);
  p[(size_t)wid*64 + lane] = e / s;
}

// ---------------- loss
__global__ __launch_bounds__(256) void loss1(const float* __restrict__ p,
    const int* __restrict__ train, const int* __restrict__ label,
    float* __restrict__ part, int ntrain){
  int lane = threadIdx.x & 63; int w = threadIdx.x >> 6;
  int gw = blockIdx.x*4 + w; int nw = gridDim.x*4;
  float acc = 0.f;
  for(int t = gw; t < ntrain; t += nw){
    int node = train[t];
    float v = p[(size_t)node*64 + lane];
    float m = wave_max(v);
    float e = expf(v - m);
    float s = wave_sum(e);
    float logp = (v - m) - logf(s);
    int lab = label[node];
    if(lane == lab) acc += logp;
  }
  acc = wave_sum(acc);
  __shared__ float ls[4];
  if(lane == 0) ls[w] = acc;
  __syncthreads();
  if(threadIdx.x == 0) part[blockIdx.x] = ls[0]+ls[1]+ls[2]+ls[3];
}

__global__ void loss2(const float* __restrict__ part, float* __restrict__ out,
                      int nb, int ntrain){
  if(threadIdx.x == 0){
    float s = 0.f;
    for(int i=0;i<nb;i++) s += part[i];
    out[0] = -s / (float)ntrain;
  }
}

extern "C" void kernel_launch(void* const* d_in, const int* in_sizes, int n_in,
                              void* d_out, int out_size, void* d_ws, size_t ws_size,
                              hipStream_t stream){
  const float* feature = (const float*)d_in[0];
  const int*   label   = (const int*)d_in[1];
  const int*   train   = (const int*)d_in[2];
  const int*   src     = (const int*)d_in[3];
  const int*   dst     = (const int*)d_in[4];
  const float* W0   = (const float*)d_in[5];
  const float* al0  = (const float*)d_in[6];
  const float* ar0  = (const float*)d_in[7];
  const float* b0   = (const float*)d_in[8];
  const float* W1   = (const float*)d_in[9];
  const float* al1  = (const float*)d_in[10];
  const float* ar1  = (const float*)d_in[11];
  const float* b1   = (const float*)d_in[12];
  const float* Wout = (const float*)d_in[13];
  const float* bout = (const float*)d_in[14];
  const float* Wfc  = (const float*)d_in[15];
  const float* bfc  = (const float*)d_in[16];
  const float* gamma= (const float*)d_in[17];
  const float* beta = (const float*)d_in[18];

  const int N  = in_sizes[1];
  const int NT = in_sizes[2];
  const int E  = in_sizes[3];

  const int nbuck  = (N + (1<<NBUCK_SH) - 1) >> NBUCK_SH;   // 196
  const int ntiles = (E + CSR_TILE - 1) / CSR_TILE;         // 391

  size_t off = 0;
  auto alloc = [&](size_t bytes)->void*{
    void* pp = (char*)d_ws + off;
    off += (bytes + 255) & ~(size_t)255;
    return pp;
  };
  unsigned* featb16 = (unsigned*)alloc((size_t)N*64*4);
  unsigned* hbuf2   = (unsigned*)alloc((size_t)N*64*4);   // also tmp slabs (12.8MB < 25.6MB)
  float* el      = (float*)alloc((size_t)N*2*4);
  float* er      = (float*)alloc((size_t)N*2*4);
  int*   rowptr  = (int*)alloc((size_t)(N+1)*4);
  int*   esrc    = (int*)alloc((size_t)E*4);
  int*   cursor  = (int*)alloc((size_t)256*4);
  int*   bbase   = (int*)alloc((size_t)(nbuck+1)*4);
  unsigned* Wt0  = (unsigned*)alloc((size_t)128*128*4);
  unsigned* Wt1  = (unsigned*)alloc((size_t)128*64*4);
  float* psum    = (float*)alloc((size_t)256*64*4);
  float* psum2   = (float*)alloc((size_t)256*64*4);
  float* scsh    = (float*)alloc(128*4);
  float* lpart   = (float*)alloc(256*4);
  float* hfc     = (float*)featb16;      // reuse: featb16 dead after agg L1
  unsigned* tmp  = hbuf2;                // reuse: hbuf2 first written by agg L0

  float* p_out   = (float*)d_out;
  float* loss_out= (float*)d_out + (size_t)N*64;

  const int nwaveblk = (N + 3) / 4;

  // ---- weight prep (bf16, transposed)
  wtrans2<<<96, 256, 0, stream>>>(W0, W1, Wt0, Wt1);

  // ---- CSR build (fused counting sort)
  hipMemsetAsync(cursor, 0, 256*4, stream);
  csrABC<<<ntiles, 256, 0, stream>>>(src, dst, cursor, tmp, E, nbuck);
  scanB<<<1, 256, 0, stream>>>(cursor, bbase, nbuck, E);
  csrD<<<nbuck, 512, 0, stream>>>(tmp, bbase, rowptr, esrc, N, E, nbuck);

  // ---- layer 0 (gemm fuses el/er epilogue)
  gemm_mfma<1><<<(N+127)/128, 256, 0, stream>>>(feature, Wt0, featb16, al0, ar0, el, er, N, 256);
  agg_kernel<<<nwaveblk, 256, 0, stream>>>(featb16, el, er, rowptr, esrc, b0, hbuf2, N);

  // ---- layer 1
  gemm_mfma<0><<<(N+127)/128, 256, 0, stream>>>(hbuf2, Wt1, featb16, al1, ar1, el, er, N, 128);
  agg_kernel<<<nwaveblk, 256, 0, stream>>>(featb16, el, er, rowptr, esrc, b1, hbuf2, N);

  // ---- dense head
  head_kernel<<<(N+63)/64, 256, 0, stream>>>(hbuf2, Wout, bout, Wfc, bfc, hfc, N);

  // ---- batchnorm
  bn_stats<<<256, 256, 0, stream>>>(hfc, psum, psum2, N);
  bn_fin<<<1, 64, 0, stream>>>(psum, psum2, gamma, beta, scsh, N, 256);
  bn_softmax<<<nwaveblk, 256, 0, stream>>>(hfc, scsh, p_out, N);

  // ---- loss
  loss1<<<40, 256, 0, stream>>>(p_out, train, label, lpart, NT);
  loss2<<<1, 64, 0, stream>>>(lpart, loss_out, 40, NT);
}